// Round 4
// baseline (276.218 us; speedup 1.0000x reference)
//
#include <hip/hip_runtime.h>

#ifndef __has_builtin
#define __has_builtin(x) 0
#endif

__device__ __forceinline__ float fast_exp2(float x) {
#if __has_builtin(__builtin_amdgcn_exp2f)
    return __builtin_amdgcn_exp2f(x);
#else
    return exp2f(x);
#endif
}

constexpr int   kB      = 256;
constexpr int   kC      = 1024;
constexpr int   kG      = 13;
constexpr int   kP      = kG * kG;                // 169
constexpr int   kParts  = 4;                      // position parts per batch
constexpr int   kMaxPP  = 43;                     // max positions per part
constexpr float kEps    = 1e-6f;
constexpr float kZ      = 17.079468445347132f;    // 2*pi*e
constexpr float kLog2e  = 1.4426950408889634f;
constexpr float kInv169 = 1.0f / 169.0f;
constexpr float kScale  = 1.0f / (256.0f * 1024.0f);

// ---------------------------------------------------------------------------
// Kernel 1: single-pass partial stats. Block = (batch b, part) with 1024
// threads; thread owns channel c=tid. Parts: start = part*42, count = 42
// (42,42,42,43) so p = start+i <= 168 is always in-bounds; for parts 0-2 the
// 43rd element is masked to zero (invD guard 1e-30 keeps 0*invD == 0).
// All <=43 x-values loaded into registers up front (deep MLP), e = 2^(x*l2e),
// per-position 64-lane butterfly -> 16 wave partials in LDS -> invD(p),
// then stats accumulate straight from the register-held e values: the input
// is read from HBM exactly once.
// ---------------------------------------------------------------------------
__global__ __launch_bounds__(1024, 4)
void part_stats_kernel(const float* __restrict__ x, float* __restrict__ ws)
{
    __shared__ float4 sTab[kP];                 // (fx, fy, fx^2, fy^2)
    __shared__ float  sP[kMaxPP * 16];          // per-position wave partials
    __shared__ float  sInvD[kMaxPP];

    const int tid   = threadIdx.x;
    const int lane  = tid & 63;
    const int wid   = tid >> 6;
    const int b     = blockIdx.x >> 2;
    const int part  = blockIdx.x & 3;
    const int start = part * 42;
    const bool full = (part == 3);              // part 3 has 43 positions

    if (tid < kP) {
        const int h = tid / kG;
        const int w = tid - h * kG;
        const float fx = (float)(h + 1);
        const float fy = (float)(w + 1);
        sTab[tid] = make_float4(fx, fy, fx * fx, fy * fy);
    }

    const float* __restrict__ xc = x + (size_t)b * kP * kC + (size_t)start * kC + tid;

    float e[kMaxPP];
    #pragma unroll
    for (int i = 0; i < kMaxPP; ++i)
        e[i] = xc[(size_t)i * kC];

    #pragma unroll
    for (int i = 0; i < kMaxPP; ++i)
        e[i] = fast_exp2(e[i] * kLog2e);

    if (!full) e[42] = 0.0f;                    // mask duplicate position

    // per-position denominators: butterfly -> lane0 writes wave partial
    #pragma unroll
    for (int i = 0; i < kMaxPP; ++i) {
        float s = e[i];
        #pragma unroll
        for (int m = 1; m < 64; m <<= 1)
            s += __shfl_xor(s, m);
        if (lane == 0) sP[i * 16 + wid] = s;
    }
    __syncthreads();

    if (tid < kMaxPP) {
        float d = 0.f;
        #pragma unroll
        for (int w = 0; w < 16; ++w)
            d += sP[tid * 16 + w];
        sInvD[tid] = 1.0f / (d + 1e-30f);       // masked position: 0*1e30 = 0
    }
    __syncthreads();

    float S0 = 0.f, S1x = 0.f, S1y = 0.f, S2x = 0.f, S2y = 0.f;
    #pragma unroll
    for (int i = 0; i < kMaxPP; ++i) {
        const float  f = e[i] * sInvD[i];
        const float4 t = sTab[start + i];
        S0  += f;
        S1x  = fmaf(t.x, f, S1x);
        S1y  = fmaf(t.y, f, S1y);
        S2x  = fmaf(t.z, f, S2x);
        S2y  = fmaf(t.w, f, S2y);
    }

    // partial stats: ws[part][b][stat][c]
    float* __restrict__ o = ws + (((size_t)part * kB + b) * 5) * kC + tid;
    o[0 * kC] = S0;
    o[1 * kC] = S1x;
    o[2 * kC] = S1y;
    o[3 * kC] = S2x;
    o[4 * kC] = S2y;
}

// ---------------------------------------------------------------------------
// Kernel 2: combine 4 parts per (b,c), det epilogue, global mean.
// ---------------------------------------------------------------------------
__global__ __launch_bounds__(1024, 4)
void combine_kernel(const float* __restrict__ ws, float* __restrict__ out)
{
    __shared__ float sred[16];

    const int tid  = threadIdx.x;
    const int lane = tid & 63;
    const int wid  = tid >> 6;
    const int b    = blockIdx.x;

    float S0 = 0.f, S1x = 0.f, S1y = 0.f, S2x = 0.f, S2y = 0.f;
    #pragma unroll
    for (int part = 0; part < kParts; ++part) {
        const float* __restrict__ o = ws + (((size_t)part * kB + b) * 5) * kC + tid;
        S0  += o[0 * kC];
        S1x += o[1 * kC];
        S1y += o[2 * kC];
        S2x += o[3 * kC];
        S2y += o[4 * kC];
    }

    const float s   = S0 + kEps;
    const float is  = 1.0f / s;
    const float mx  = S1x * is;
    const float my  = S1y * is;
    const float nx  = S2x - mx * (2.0f * S1x - mx * S0);
    const float ny  = S2y - my * (2.0f * S1y - my * S0);
    const float t   = (nx + ny) * is * kInv169;
    float det = t * t * kZ;

    #pragma unroll
    for (int m = 1; m < 64; m <<= 1)
        det += __shfl_xor(det, m);

    if (lane == 0) sred[wid] = det;
    __syncthreads();
    if (wid == 0) {
        float v = (lane < 16) ? sred[lane] : 0.0f;
        #pragma unroll
        for (int m = 1; m < 16; m <<= 1)
            v += __shfl_xor(v, m);
        if (lane == 0) atomicAdd(out, v * kScale);
    }
}

extern "C" void kernel_launch(void* const* d_in, const int* in_sizes, int n_in,
                              void* d_out, int out_size, void* d_ws, size_t ws_size,
                              hipStream_t stream)
{
    const float* x   = (const float*)d_in[0];
    float*       out = (float*)d_out;
    float*       ws  = (float*)d_ws;   // 4*256*5*1024 floats = 20 MB

    hipMemsetAsync(out, 0, sizeof(float) * (size_t)out_size, stream);
    part_stats_kernel<<<dim3(kB * kParts), dim3(1024), 0, stream>>>(x, ws);
    combine_kernel  <<<dim3(kB),           dim3(1024), 0, stream>>>(ws, out);
}

// Round 5
// 265.743 us; speedup vs baseline: 1.0394x; 1.0394x over previous
//
#include <hip/hip_runtime.h>

#ifndef __has_builtin
#define __has_builtin(x) 0
#endif

__device__ __forceinline__ float fast_exp2(float x) {
#if __has_builtin(__builtin_amdgcn_exp2f)
    return __builtin_amdgcn_exp2f(x);
#else
    return exp2f(x);
#endif
}

constexpr int   kB      = 256;
constexpr int   kC      = 1024;
constexpr int   kG      = 13;
constexpr int   kP      = kG * kG;                // 169
constexpr float kEps    = 1e-6f;
constexpr float kZ      = 17.079468445347132f;    // 2*pi*e
constexpr float kLog2e  = 1.4426950408889634f;
constexpr float kInv169 = 1.0f / 169.0f;
constexpr float kScale  = 1.0f / (256.0f * 1024.0f);

// One block per batch. Phase 1: wave-per-position row sums (6 DS ops per
// position only), software-pipelined so the next position's 4 float4 loads
// are in flight during the current butterfly; stores 1/D(p) in LDS (no
// log2/exp2 round-trip). Phase 2: thread owns channel c=tid; h-loop is
// '#pragma unroll 1' (prevents 169-load hoist / register blowup — the R1
// spill failure mode) with explicit prefetch of row h+1 (13 loads in
// flight), 6 VALU + 1 exp2 per element, zero cross-lane ops.
__global__ __launch_bounds__(1024, 4)
void constrain_loss_fused2(const float* __restrict__ x, float* __restrict__ out)
{
    __shared__ float sInvD[kP];
    __shared__ float sred[16];

    const int tid  = threadIdx.x;
    const int lane = tid & 63;
    const int wid  = tid >> 6;
    const int b    = blockIdx.x;

    const float* __restrict__ xb = x + (size_t)b * kP * kC;

    // ---------------- phase 1: per-position 1/D, pipelined ----------------
    {
        int p = wid;
        const float4* __restrict__ s0 = (const float4*)(xb + (size_t)p * kC);
        float4 c0 = s0[lane];
        float4 c1 = s0[lane + 64];
        float4 c2 = s0[lane + 128];
        float4 c3 = s0[lane + 192];

        while (p < kP) {
            const int pn = p + 16;
            float4 n0, n1, n2, n3;
            if (pn < kP) {
                const float4* __restrict__ s1 = (const float4*)(xb + (size_t)pn * kC);
                n0 = s1[lane];
                n1 = s1[lane + 64];
                n2 = s1[lane + 128];
                n3 = s1[lane + 192];
            }

            float s =
                (fast_exp2(c0.x * kLog2e) + fast_exp2(c0.y * kLog2e)) +
                (fast_exp2(c0.z * kLog2e) + fast_exp2(c0.w * kLog2e)) +
                (fast_exp2(c1.x * kLog2e) + fast_exp2(c1.y * kLog2e)) +
                (fast_exp2(c1.z * kLog2e) + fast_exp2(c1.w * kLog2e)) +
                (fast_exp2(c2.x * kLog2e) + fast_exp2(c2.y * kLog2e)) +
                (fast_exp2(c2.z * kLog2e) + fast_exp2(c2.w * kLog2e)) +
                (fast_exp2(c3.x * kLog2e) + fast_exp2(c3.y * kLog2e)) +
                (fast_exp2(c3.z * kLog2e) + fast_exp2(c3.w * kLog2e));

            #pragma unroll
            for (int m = 1; m < 64; m <<= 1)
                s += __shfl_xor(s, m);

            if (lane == 0) sInvD[p] = 1.0f / s;

            c0 = n0; c1 = n1; c2 = n2; c3 = n3;
            p = pn;
        }
    }
    __syncthreads();

    // ---------------- phase 2: per-channel moments (c = tid) ----------------
    const float* __restrict__ xc = xb + tid;

    float S0 = 0.f, S1x = 0.f, S2x = 0.f, S1y = 0.f, S2y = 0.f;

    float v[kG], vn[kG];
    #pragma unroll
    for (int w = 0; w < kG; ++w)
        v[w] = xc[(size_t)w * kC];

    #pragma unroll 1
    for (int h = 0; h < kG; ++h) {
        if (h + 1 < kG) {
            const float* __restrict__ rn = xc + (size_t)(h + 1) * kG * kC;
            #pragma unroll
            for (int w = 0; w < kG; ++w)
                vn[w] = rn[(size_t)w * kC];
        }

        float t0 = 0.f, t1 = 0.f, t2 = 0.f;
        #pragma unroll
        for (int w = 0; w < kG; ++w) {
            const float e = fast_exp2(v[w] * kLog2e) * sInvD[h * kG + w];
            t0 += e;
            t1 = fmaf((float)(w + 1), e, t1);
            t2 = fmaf((float)((w + 1) * (w + 1)), e, t2);
        }
        const float fx = (float)(h + 1);
        S0  += t0;
        S1x  = fmaf(fx,      t0, S1x);
        S2x  = fmaf(fx * fx, t0, S2x);
        S1y += t1;
        S2y += t2;

        #pragma unroll
        for (int w = 0; w < kG; ++w)
            v[w] = vn[w];
    }

    // ---------------- epilogue: per-channel det, block reduce ----------------
    const float s   = S0 + kEps;
    const float is  = 1.0f / s;
    const float mx  = S1x * is;
    const float my  = S1y * is;
    const float nx  = S2x - mx * (2.0f * S1x - mx * S0);
    const float ny  = S2y - my * (2.0f * S1y - my * S0);
    const float t   = (nx + ny) * is * kInv169;   // x_var + y_var
    float det = t * t * kZ;

    #pragma unroll
    for (int m = 1; m < 64; m <<= 1)
        det += __shfl_xor(det, m);

    if (lane == 0) sred[wid] = det;
    __syncthreads();
    if (wid == 0) {
        float v2 = (lane < 16) ? sred[lane] : 0.0f;
        #pragma unroll
        for (int m = 1; m < 16; m <<= 1)
            v2 += __shfl_xor(v2, m);
        if (lane == 0) atomicAdd(out, v2 * kScale);
    }
}

extern "C" void kernel_launch(void* const* d_in, const int* in_sizes, int n_in,
                              void* d_out, int out_size, void* d_ws, size_t ws_size,
                              hipStream_t stream)
{
    const float* x   = (const float*)d_in[0];
    float*       out = (float*)d_out;

    hipMemsetAsync(out, 0, sizeof(float) * (size_t)out_size, stream);
    constrain_loss_fused2<<<dim3(kB), dim3(1024), 0, stream>>>(x, out);
}